// Round 5
// baseline (287.339 us; speedup 1.0000x reference)
//
#include <hip/hip_runtime.h>
#include <stdint.h>

// B=8, OBJ=128, INP=64, HID=256, D=192.
// pair: out^T = W^T·h^T per (b,i). Wave = (n-half 128) x (j-half 64).
// Weights for a whole layer live in REGISTERS (64 short8 = 256 VGPR), loaded
// in one burst per layer -> inner loop is pure ds_read_b128 + MFMA (no vmcnt).
// Next-layer W burst issues before the writeback so pack/ds_write/barrier
// hides its L2 latency; barriers drain lgkmcnt only (vmcnt stays in flight).

#define HID 256
#define NOBJ 128
#define NROW 1024   // B*OBJ

typedef __attribute__((ext_vector_type(8))) short short8;
typedef __attribute__((ext_vector_type(4))) float float4v;
typedef __attribute__((ext_vector_type(2))) unsigned int uint2v;

__device__ __forceinline__ unsigned int f2bf_u(float f) {
    unsigned int u = __builtin_bit_cast(unsigned int, f);
    u += 0x7fffu + ((u >> 16) & 1u);   // RNE
    return u >> 16;
}
__device__ __forceinline__ unsigned int pack2(float a, float b) {
    return f2bf_u(a) | (f2bf_u(b) << 16);
}
__device__ __forceinline__ float relu(float v) { return v > 0.f ? v : 0.f; }

// LDS-only barrier: leaves global-load (vmcnt) prefetches in flight.
__device__ __forceinline__ void lds_barrier() {
    asm volatile("s_waitcnt lgkmcnt(0)\n\ts_barrier" ::: "memory");
}

// ---- setup: blocks [0,48) coalesced transpose w1..w3 -> bf16 wt[l][n][k];
//             blocks [48,304) encoder (4 rows each, fold b_enc into ea)
__global__ void setup_kernel(const float* __restrict__ x0, const float* __restrict__ x1,
                             const float* __restrict__ x2, const float* __restrict__ w_enc,
                             const float* __restrict__ b_enc,
                             const float* __restrict__ w1, const float* __restrict__ w2,
                             const float* __restrict__ w3,
                             unsigned short* __restrict__ wt,
                             float* __restrict__ ea, float* __restrict__ eb) {
    const int bx = blockIdx.x, t = threadIdx.x;
    __shared__ float tile[64][65];
    __shared__ float xs[4][192];
    if (bx < 48) {
        const int m = bx / 16, tl = bx % 16;
        const int n0 = (tl & 3) * 64, k0 = (tl >> 2) * 64;
        const float* w = (m == 0) ? w1 : (m == 1) ? w2 : w3;
        const int nn = t & 63, kk = t >> 6;
#pragma unroll
        for (int it = 0; it < 16; ++it) {
            int k = kk + it * 4;
            tile[k][nn] = w[(k0 + k) * 256 + n0 + nn];   // coalesced read
        }
        __syncthreads();
        const int k2 = t & 63, nb = t >> 6;
#pragma unroll
        for (int it = 0; it < 16; ++it) {
            int n = nb + it * 4;
            wt[m * 65536 + (n0 + n) * 256 + k0 + k2] =
                (unsigned short)f2bf_u(tile[k2][n]);      // coalesced write
        }
        return;
    }
    const int e = bx - 48;                 // 256 groups x 4 rows
    for (int idx = t; idx < 768; idx += 256) {
        int r = idx / 192, d = idx % 192;
        int row = e * 4 + r;
        float v = (d < 64) ? x0[row * 64 + d]
                : (d < 128) ? x1[row * 64 + d - 64]
                : x2[row * 64 + d - 128];
        xs[r][d] = v;
    }
    __syncthreads();
    float aA[4] = {0.f, 0.f, 0.f, 0.f}, aB[4] = {0.f, 0.f, 0.f, 0.f};
#pragma unroll 8
    for (int d = 0; d < 192; ++d) {
        float wa = w_enc[d * 256 + t];
        float wb = w_enc[(192 + d) * 256 + t];
#pragma unroll
        for (int r = 0; r < 4; ++r) { aA[r] += xs[r][d] * wa; aB[r] += xs[r][d] * wb; }
    }
    float be = b_enc[t];
#pragma unroll
    for (int r = 0; r < 4; ++r) {
        ea[(e * 4 + r) * 256 + t] = aA[r] + be;
        eb[(e * 4 + r) * 256 + t] = aB[r];
    }
}

// ---- pair MLP: grid 1024, one WG per (b,i). 64 KB LDS h (128 j x 256 k),
//      swizzle: elem(j,k) at j*256 + ((k>>3 ^ (j&31))<<3) + (k&7).
//      Wave wv: nh = wv&1 (n 0-127/128-255), jh = wv>>1 (j 0-63/64-127).
__global__ __launch_bounds__(256, 1) void pair_kernel(
        const float* __restrict__ ea, const float* __restrict__ eb,
        const unsigned short* __restrict__ wt,
        const float* __restrict__ b1, const float* __restrict__ b2,
        const float* __restrict__ b3, float* __restrict__ pooled) {
    __shared__ __align__(16) unsigned short hbuf[128 * 256];   // 64 KB
    __shared__ float red[2][256];                              // 2 KB

    const int w = blockIdx.x, b = w >> 7;
    const int t = threadIdx.x, wv = t >> 6, lane = t & 63;
    const int lo = lane & 15, hi = lane >> 4;
    const int nh = wv & 1, jh = wv >> 1;
    const int n0 = nh * 128, j0 = jh * 64;

    const unsigned short* aptr = wt + (n0 + lo) * 256 + hi * 8;

    // preamble: h0[j][k] = relu(ea[w][k] + eb[b*128+j][k]); wave wv fills j=wv*32..+31
    {
        const float4v va = *(const float4v*)(ea + w * 256 + lane * 4);
        const float* ebbase = eb + (b * NOBJ) * 256;
        const int c = lane >> 1, sub = (lane & 1) * 4;
#pragma unroll 4
        for (int jj = 0; jj < 32; ++jj) {
            const int j = wv * 32 + jj;
            float4v vb = *(const float4v*)(ebbase + j * 256 + lane * 4);
            float f0 = relu(va[0] + vb[0]);
            float f1 = relu(va[1] + vb[1]);
            float f2 = relu(va[2] + vb[2]);
            float f3 = relu(va[3] + vb[3]);
            int addr = j * 256 + ((c ^ (j & 31)) << 3) + sub;
            *(uint2v*)(hbuf + addr) = (uint2v){pack2(f0, f1), pack2(f2, f3)};
        }
    }

    // layer-0 weight burst: 64 short8 = 256 VGPRs, issued before the barrier
    short8 wreg[8][8];   // [nt][kb]
#pragma unroll
    for (int nt = 0; nt < 8; ++nt)
#pragma unroll
        for (int kb = 0; kb < 8; ++kb)
            wreg[nt][kb] = *(const short8*)(aptr + nt * 4096 + kb * 32);

    lds_barrier();

    int jbase[4], jx[4];
#pragma unroll
    for (int jt = 0; jt < 4; ++jt) {
        int jr = j0 + jt * 16 + lo;
        jbase[jt] = jr * 256;
        jx[jt] = jr & 31;
    }

    float4v acc[8][4];   // [nt][jt]

#pragma unroll
    for (int l = 0; l < 3; ++l) {
        const float* bias = (l == 0) ? b1 : (l == 1) ? b2 : b3;
#pragma unroll
        for (int nt = 0; nt < 8; ++nt) {
            float4v bv = *(const float4v*)(bias + n0 + nt * 16 + hi * 4);
#pragma unroll
            for (int jt = 0; jt < 4; ++jt) acc[nt][jt] = bv;
        }
        // inner loop: pure LDS + MFMA, no global traffic
#pragma unroll
        for (int kb = 0; kb < 8; ++kb) {
            short8 bfr[4];
#pragma unroll
            for (int jt = 0; jt < 4; ++jt)
                bfr[jt] = *(const short8*)(hbuf + jbase[jt] +
                              (((kb * 4 + hi) ^ jx[jt]) << 3));
#pragma unroll
            for (int nt = 0; nt < 8; ++nt)
#pragma unroll
                for (int jt = 0; jt < 4; ++jt)
                    acc[nt][jt] = __builtin_amdgcn_mfma_f32_16x16x32_bf16(
                        wreg[nt][kb], bfr[jt], acc[nt][jt], 0, 0, 0);
        }

        // issue next layer's W burst NOW; writeback below hides its latency
        if (l < 2) {
#pragma unroll
            for (int nt = 0; nt < 8; ++nt)
#pragma unroll
                for (int kb = 0; kb < 8; ++kb)
                    wreg[nt][kb] = *(const short8*)(aptr + (l + 1) * 65536 +
                                                    nt * 4096 + kb * 32);
        }
        lds_barrier();   // all hbuf reads of layer l done

        if (l < 2) {
            // C rows n = n0+nt*16+hi*4+{0..3} (contiguous), cols j = j0+jt*16+lo
#pragma unroll
            for (int nt = 0; nt < 8; ++nt) {
                const int nb_ = n0 + nt * 16 + hi * 4;
                const int cn = nb_ >> 3, sub = nb_ & 7;
#pragma unroll
                for (int jt = 0; jt < 4; ++jt) {
                    float4v v = acc[nt][jt];
                    int j = j0 + jt * 16 + lo;
                    int addr = j * 256 + ((cn ^ (j & 31)) << 3) + sub;
                    *(uint2v*)(hbuf + addr) = (uint2v){
                        pack2(relu(v[0]), relu(v[1])),
                        pack2(relu(v[2]), relu(v[3]))};
                }
            }
            lds_barrier();
        } else {
            // mean over j: sum 4 jt + shfl over 16 lo-lanes -> red[jh][n]
#pragma unroll
            for (int nt = 0; nt < 8; ++nt)
#pragma unroll
                for (int r = 0; r < 4; ++r) {
                    float s = acc[nt][0][r] + acc[nt][1][r] + acc[nt][2][r] + acc[nt][3][r];
                    s += __shfl_xor(s, 1);
                    s += __shfl_xor(s, 2);
                    s += __shfl_xor(s, 4);
                    s += __shfl_xor(s, 8);
                    if (lo == 0) red[jh][n0 + nt * 16 + hi * 4 + r] = s;
                }
            lds_barrier();
            pooled[w * 256 + t] = (red[0][t] + red[1][t]) * 0.0078125f;
        }
    }
}

// ---- decoder: 256 WGs x 4 rows.
__global__ void dec_kernel(const float* __restrict__ pooled,
                           const float* __restrict__ wd1, const float* __restrict__ bd1,
                           const float* __restrict__ wd2, const float* __restrict__ bd2,
                           float* __restrict__ out) {
    __shared__ float ps[4][256];
    __shared__ float t1[4][260];
    const int g = blockIdx.x, t = threadIdx.x;
#pragma unroll
    for (int r = 0; r < 4; ++r) ps[r][t] = pooled[(g * 4 + r) * 256 + t];
    __syncthreads();
    {
        float acc[4];
        float bv = bd1[t];
#pragma unroll
        for (int r = 0; r < 4; ++r) acc[r] = bv;
#pragma unroll 8
        for (int k = 0; k < 256; ++k) {
            float wv = wd1[k * 256 + t];
#pragma unroll
            for (int r = 0; r < 4; ++r) acc[r] += ps[r][k] * wv;
        }
#pragma unroll
        for (int r = 0; r < 4; ++r) t1[r][t] = relu(acc[r]);
    }
    __syncthreads();
    {
        const int o = t & 63, rr = t >> 6;
        float a = 0.f;
#pragma unroll 8
        for (int k = 0; k < 256; ++k) a += t1[rr][k] * wd2[k * 64 + o];
        out[(g * 4 + rr) * 64 + o] = a + bd2[o];
    }
}

extern "C" void kernel_launch(void* const* d_in, const int* in_sizes, int n_in,
                              void* d_out, int out_size, void* d_ws, size_t ws_size,
                              hipStream_t stream) {
    const float* x0    = (const float*)d_in[0];
    const float* x1    = (const float*)d_in[1];
    const float* x2    = (const float*)d_in[2];
    const float* w_enc = (const float*)d_in[3];
    const float* b_enc = (const float*)d_in[4];
    const float* w1    = (const float*)d_in[5];
    const float* b1    = (const float*)d_in[6];
    const float* w2    = (const float*)d_in[7];
    const float* b2    = (const float*)d_in[8];
    const float* w3    = (const float*)d_in[9];
    const float* b3    = (const float*)d_in[10];
    const float* wd1   = (const float*)d_in[11];
    const float* bd1   = (const float*)d_in[12];
    const float* wd2   = (const float*)d_in[13];
    const float* bd2   = (const float*)d_in[14];
    float* out = (float*)d_out;

    // workspace: wt (384KB) | ea (1MB) | eb (1MB) | pooled (1MB)
    unsigned short* wt = (unsigned short*)d_ws;
    float* ea     = (float*)((char*)d_ws + 3 * 65536 * sizeof(unsigned short));
    float* eb     = ea + NROW * HID;
    float* pooled = eb + NROW * HID;

    setup_kernel<<<304, 256, 0, stream>>>(x0, x1, x2, w_enc, b_enc, w1, w2, w3, wt, ea, eb);
    pair_kernel<<<NROW, 256, 0, stream>>>(ea, eb, wt, b1, b2, b3, pooled);
    dec_kernel<<<256, 256, 0, stream>>>(pooled, wd1, bd1, wd2, bd2, out);
}

// Round 6
// 233.215 us; speedup vs baseline: 1.2321x; 1.2321x over previous
//
#include <hip/hip_runtime.h>
#include <stdint.h>

// B=8, OBJ=128, INP=64, HID=256, D=192.
// pair: out^T = W^T·h^T per (b,i,j-half). Wave tile n=64 x j=64, acc[4][4]
// (->AGPR), af/bfr double-buffered (32+32 VGPR) -> ~160 total regs: fits the
// 2-waves/SIMD budget declared by launch_bounds WITHOUT spilling (R3-R5's
// WRITE_SIZE anomaly was launch-bounds-forced scratch spill in the K-loop).

#define HID 256
#define NOBJ 128
#define NROW 1024   // B*OBJ

typedef __attribute__((ext_vector_type(8))) short short8;
typedef __attribute__((ext_vector_type(4))) float float4v;
typedef __attribute__((ext_vector_type(2))) unsigned int uint2v;

__device__ __forceinline__ unsigned int f2bf_u(float f) {
    unsigned int u = __builtin_bit_cast(unsigned int, f);
    u += 0x7fffu + ((u >> 16) & 1u);   // RNE
    return u >> 16;
}
__device__ __forceinline__ unsigned int pack2(float a, float b) {
    return f2bf_u(a) | (f2bf_u(b) << 16);
}
__device__ __forceinline__ float relu(float v) { return v > 0.f ? v : 0.f; }

// LDS-only barrier: leaves global-load (vmcnt) prefetches in flight.
__device__ __forceinline__ void lds_barrier() {
    asm volatile("s_waitcnt lgkmcnt(0)\n\ts_barrier" ::: "memory");
}

// ---- setup: blocks [0,48) coalesced transpose w1..w3 -> bf16 wt[l][n][k];
//             blocks [48,560) encoder (2 rows each, fold b_enc into ea)
__global__ void setup_kernel(const float* __restrict__ x0, const float* __restrict__ x1,
                             const float* __restrict__ x2, const float* __restrict__ w_enc,
                             const float* __restrict__ b_enc,
                             const float* __restrict__ w1, const float* __restrict__ w2,
                             const float* __restrict__ w3,
                             unsigned short* __restrict__ wt,
                             float* __restrict__ ea, float* __restrict__ eb) {
    const int bx = blockIdx.x, t = threadIdx.x;
    __shared__ float tile[64][65];
    __shared__ float xs[2][192];
    if (bx < 48) {
        const int m = bx / 16, tl = bx % 16;
        const int n0 = (tl & 3) * 64, k0 = (tl >> 2) * 64;
        const float* w = (m == 0) ? w1 : (m == 1) ? w2 : w3;
        const int nn = t & 63, kk = t >> 6;
#pragma unroll
        for (int it = 0; it < 16; ++it) {
            int k = kk + it * 4;
            tile[k][nn] = w[(k0 + k) * 256 + n0 + nn];   // coalesced read
        }
        __syncthreads();
        const int k2 = t & 63, nb = t >> 6;
#pragma unroll
        for (int it = 0; it < 16; ++it) {
            int n = nb + it * 4;
            wt[m * 65536 + (n0 + n) * 256 + k0 + k2] =
                (unsigned short)f2bf_u(tile[k2][n]);      // coalesced write
        }
        return;
    }
    const int e = bx - 48;                 // 512 groups x 2 rows
    for (int idx = t; idx < 384; idx += 256) {
        int r = idx / 192, d = idx % 192;
        int row = e * 2 + r;
        float v = (d < 64) ? x0[row * 64 + d]
                : (d < 128) ? x1[row * 64 + d - 64]
                : x2[row * 64 + d - 128];
        xs[r][d] = v;
    }
    __syncthreads();
    float aA[2] = {0.f, 0.f}, aB[2] = {0.f, 0.f};
#pragma unroll 16
    for (int d = 0; d < 192; ++d) {
        float wa = w_enc[d * 256 + t];
        float wb = w_enc[(192 + d) * 256 + t];
#pragma unroll
        for (int r = 0; r < 2; ++r) { aA[r] += xs[r][d] * wa; aB[r] += xs[r][d] * wb; }
    }
    float be = b_enc[t];
#pragma unroll
    for (int r = 0; r < 2; ++r) {
        ea[(e * 2 + r) * 256 + t] = aA[r] + be;
        eb[(e * 2 + r) * 256 + t] = aB[r];
    }
}

// ---- pair MLP: grid 2048 = (b,i) x j-half. 64 j-rows/WG, 32 KB LDS h,
//      swizzle: elem(j,k) at j*256 + ((k>>3 ^ (j&31))<<3) + (k&7).
//      Wave wv owns n-quarter n0 = wv*64; all waves share the j=64 rows.
__global__ __launch_bounds__(256, 2) void pair_kernel(
        const float* __restrict__ ea, const float* __restrict__ eb,
        const unsigned short* __restrict__ wt,
        const float* __restrict__ b1, const float* __restrict__ b2,
        const float* __restrict__ b3, float* __restrict__ pp) {
    __shared__ __align__(16) unsigned short hbuf[64 * 256];   // 32 KB

    const int bx = blockIdx.x;
    const int w = bx >> 1, half = bx & 1, b = w >> 7;
    const int t = threadIdx.x, wv = t >> 6, lane = t & 63;
    const int lo = lane & 15, hi = lane >> 4;
    const int n0 = wv * 64;

    const unsigned short* aptr = wt + (n0 + lo) * 256 + hi * 8;

    short8 af[2][4], bfr[2][4];
    // flat A-pipeline: layer0/kb0 issued before the preamble
#pragma unroll
    for (int nt = 0; nt < 4; ++nt)
        af[0][nt] = *(const short8*)(aptr + nt * 4096);

    // preamble: h0[j][k] = relu(ea[w][k] + eb[b*128+half*64+j][k]); wave fills j=wv*16..+15
    {
        const float4v va = *(const float4v*)(ea + w * 256 + lane * 4);
        const float* ebbase = eb + (b * NOBJ + half * 64) * 256;
        const int c = lane >> 1, sub = (lane & 1) * 4;
#pragma unroll 4
        for (int jj = 0; jj < 16; ++jj) {
            const int j = wv * 16 + jj;
            float4v vb = *(const float4v*)(ebbase + j * 256 + lane * 4);
            int addr = j * 256 + ((c ^ (j & 31)) << 3) + sub;
            *(uint2v*)(hbuf + addr) = (uint2v){
                pack2(relu(va[0] + vb[0]), relu(va[1] + vb[1])),
                pack2(relu(va[2] + vb[2]), relu(va[3] + vb[3]))};
        }
    }
    lds_barrier();

    int jbase[4], jx[4];
#pragma unroll
    for (int jt = 0; jt < 4; ++jt) {
        int jr = jt * 16 + lo;
        jbase[jt] = jr * 256;
        jx[jt] = jr & 31;
    }
    // bfr kb=0 of layer 0
#pragma unroll
    for (int jt = 0; jt < 4; ++jt)
        bfr[0][jt] = *(const short8*)(hbuf + jbase[jt] + ((hi ^ jx[jt]) << 3));

    float4v acc[4][4];   // [nt][jt]

#pragma unroll
    for (int l = 0; l < 3; ++l) {
        const float* bias = (l == 0) ? b1 : (l == 1) ? b2 : b3;
#pragma unroll
        for (int nt = 0; nt < 4; ++nt) {
            float4v bv = *(const float4v*)(bias + n0 + nt * 16 + hi * 4);
#pragma unroll
            for (int jt = 0; jt < 4; ++jt) acc[nt][jt] = bv;
        }
#pragma unroll
        for (int kb = 0; kb < 8; ++kb) {
            const int g = l * 8 + kb, gp = g + 1;
            if (gp < 24) {   // prefetch next step's A (crosses layer boundaries)
                const int lp = gp >> 3, kp = gp & 7;
#pragma unroll
                for (int nt = 0; nt < 4; ++nt)
                    af[gp & 1][nt] = *(const short8*)(aptr + lp * 65536 + nt * 4096 + kp * 32);
            }
            if (kb < 7) {    // prefetch next step's B from LDS
#pragma unroll
                for (int jt = 0; jt < 4; ++jt)
                    bfr[(kb + 1) & 1][jt] = *(const short8*)(hbuf + jbase[jt] +
                        ((((kb + 1) * 4 + hi) ^ jx[jt]) << 3));
            }
#pragma unroll
            for (int nt = 0; nt < 4; ++nt)
#pragma unroll
                for (int jt = 0; jt < 4; ++jt)
                    acc[nt][jt] = __builtin_amdgcn_mfma_f32_16x16x32_bf16(
                        af[g & 1][nt], bfr[kb & 1][jt], acc[nt][jt], 0, 0, 0);
        }
        lds_barrier();   // hbuf reads of layer l done; af prefetch stays in flight

        if (l < 2) {
            // C rows n = n0+nt*16+hi*4+{0..3} (contiguous), cols j = jt*16+lo
#pragma unroll
            for (int nt = 0; nt < 4; ++nt) {
                const int nb_ = n0 + nt * 16 + hi * 4;
                const int cn = nb_ >> 3, sub = nb_ & 7;
#pragma unroll
                for (int jt = 0; jt < 4; ++jt) {
                    float4v v = acc[nt][jt];
                    int j = jt * 16 + lo;
                    int addr = j * 256 + ((cn ^ (j & 31)) << 3) + sub;
                    *(uint2v*)(hbuf + addr) = (uint2v){
                        pack2(relu(v[0]), relu(v[1])),
                        pack2(relu(v[2]), relu(v[3]))};
                }
            }
            lds_barrier();
            // bfr kb=0 of next layer
#pragma unroll
            for (int jt = 0; jt < 4; ++jt)
                bfr[0][jt] = *(const short8*)(hbuf + jbase[jt] + ((hi ^ jx[jt]) << 3));
        } else {
            // partial mean over this WG's 64 j (bias incl. per row; /128 + dec sums halves)
#pragma unroll
            for (int nt = 0; nt < 4; ++nt)
#pragma unroll
                for (int r = 0; r < 4; ++r) {
                    float s = acc[nt][0][r] + acc[nt][1][r] + acc[nt][2][r] + acc[nt][3][r];
                    s += __shfl_xor(s, 1);
                    s += __shfl_xor(s, 2);
                    s += __shfl_xor(s, 4);
                    s += __shfl_xor(s, 8);
                    if (lo == 0)
                        pp[half * (NROW * HID) + w * 256 + n0 + nt * 16 + hi * 4 + r]
                            = s * 0.0078125f;
                }
        }
    }
}

// ---- decoder: 256 WGs x 4 rows. ps = pp_half0 + pp_half1 (= mean + b3).
__global__ void dec_kernel(const float* __restrict__ pp,
                           const float* __restrict__ wd1, const float* __restrict__ bd1,
                           const float* __restrict__ wd2, const float* __restrict__ bd2,
                           float* __restrict__ out) {
    __shared__ float ps[4][256];
    __shared__ float t1[4][260];
    const int g = blockIdx.x, t = threadIdx.x;
#pragma unroll
    for (int r = 0; r < 4; ++r) {
        int row = g * 4 + r;
        ps[r][t] = pp[row * 256 + t] + pp[NROW * HID + row * 256 + t];
    }
    __syncthreads();
    {
        float acc[4];
        float bv = bd1[t];
#pragma unroll
        for (int r = 0; r < 4; ++r) acc[r] = bv;
#pragma unroll 16
        for (int k = 0; k < 256; ++k) {
            float wv = wd1[k * 256 + t];
#pragma unroll
            for (int r = 0; r < 4; ++r) acc[r] += ps[r][k] * wv;
        }
#pragma unroll
        for (int r = 0; r < 4; ++r) t1[r][t] = relu(acc[r]);
    }
    __syncthreads();
    {
        const int o = t & 63, rr = t >> 6;
        float a = 0.f;
#pragma unroll 16
        for (int k = 0; k < 256; ++k) a += t1[rr][k] * wd2[k * 64 + o];
        out[(g * 4 + rr) * 64 + o] = a + bd2[o];
    }
}

extern "C" void kernel_launch(void* const* d_in, const int* in_sizes, int n_in,
                              void* d_out, int out_size, void* d_ws, size_t ws_size,
                              hipStream_t stream) {
    const float* x0    = (const float*)d_in[0];
    const float* x1    = (const float*)d_in[1];
    const float* x2    = (const float*)d_in[2];
    const float* w_enc = (const float*)d_in[3];
    const float* b_enc = (const float*)d_in[4];
    const float* w1    = (const float*)d_in[5];
    const float* b1    = (const float*)d_in[6];
    const float* w2    = (const float*)d_in[7];
    const float* b2    = (const float*)d_in[8];
    const float* w3    = (const float*)d_in[9];
    const float* b3    = (const float*)d_in[10];
    const float* wd1   = (const float*)d_in[11];
    const float* bd1   = (const float*)d_in[12];
    const float* wd2   = (const float*)d_in[13];
    const float* bd2   = (const float*)d_in[14];
    float* out = (float*)d_out;

    // workspace: wt (384KB) | ea (1MB) | eb (1MB) | pp (2MB, two j-halves)
    unsigned short* wt = (unsigned short*)d_ws;
    float* ea = (float*)((char*)d_ws + 3 * 65536 * sizeof(unsigned short));
    float* eb = ea + NROW * HID;
    float* pp = eb + NROW * HID;

    setup_kernel<<<560, 256, 0, stream>>>(x0, x1, x2, w_enc, b_enc, w1, w2, w3, wt, ea, eb);
    pair_kernel<<<2048, 256, 0, stream>>>(ea, eb, wt, b1, b2, b3, pp);
    dec_kernel<<<256, 256, 0, stream>>>(pp, wd1, bd1, wd2, bd2, out);
}